// Round 10
// baseline (1160.991 us; speedup 1.0000x reference)
//
#include <hip/hip_runtime.h>
#include <math.h>

#define HN 512   // hidden states
#define HM 4096  // emission symbols
#define HB 64    // batch
#define HT 512   // max seq len

// ---- 4-bit dot path selection (encoding must match between prep + fwd) ----
#if __has_builtin(__builtin_amdgcn_udot8)
  #define ENC_BIASED 0
  __device__ __forceinline__ int dot8q(unsigned int a, unsigned int b, int c){
    return (int)__builtin_amdgcn_udot8(a, b, (unsigned int)c, false);
  }
#elif __has_builtin(__builtin_amdgcn_sdot8)
  #define ENC_BIASED 1
  __device__ __forceinline__ int dot8q(unsigned int a, unsigned int b, int c){
    return __builtin_amdgcn_sdot8((int)a, (int)b, c, false);
  }
#else
  #define ENC_BIASED 0
  __device__ __forceinline__ int dot4u8f(unsigned int a, unsigned int b, int c){
#if __has_builtin(__builtin_amdgcn_sdot4)
    return __builtin_amdgcn_sdot4((int)a, (int)b, c, false);   // vals<=15, sign-safe
#else
    c += (int)(a & 0xffu)       * (int)(b & 0xffu);
    c += (int)((a>>8) & 0xffu)  * (int)((b>>8) & 0xffu);
    c += (int)((a>>16) & 0xffu) * (int)((b>>16) & 0xffu);
    c += (int)(a>>24)           * (int)(b>>24);
    return c;
#endif
  }
  __device__ __forceinline__ int dot8q(unsigned int a, unsigned int b, int c){
    unsigned int al = a & 0x0F0F0F0Fu, ah = (a>>4) & 0x0F0F0F0Fu;
    unsigned int bl = b & 0x0F0F0F0Fu, bh = (b>>4) & 0x0F0F0F0Fu;
    c = dot4u8f(al, bl, c);
    return dot4u8f(ah, bh, c);
  }
#endif

__device__ __forceinline__ float wsum(float v){
  #pragma unroll
  for(int o=32;o>0;o>>=1) v += __shfl_xor(v,o,64);
  return v;
}
__device__ __forceinline__ float wmax(float v){
  #pragma unroll
  for(int o=32;o>0;o>>=1) v = fmaxf(v,__shfl_xor(v,o,64));
  return v;
}

__device__ __forceinline__ float blockSum512(float v, float* red, float* bc){
  v = wsum(v);
  if((threadIdx.x & 63)==0) red[threadIdx.x>>6] = v;
  __syncthreads();
  if(threadIdx.x < 64){
    float s = (threadIdx.x<8)? red[threadIdx.x] : 0.0f;
    #pragma unroll
    for(int o=4;o>0;o>>=1) s += __shfl_xor(s,o,64);
    if(threadIdx.x==0) *bc = s;
  }
  __syncthreads();
  return *bc;
}
__device__ __forceinline__ float blockMax512(float v, float* red, float* bc){
  v = wmax(v);
  if((threadIdx.x & 63)==0) red[threadIdx.x>>6] = v;
  __syncthreads();
  if(threadIdx.x < 64){
    float s = (threadIdx.x<8)? red[threadIdx.x] : -INFINITY;
    #pragma unroll
    for(int o=4;o>0;o>>=1) s = fmaxf(s, __shfl_xor(s,o,64));
    if(threadIdx.x==0) *bc = s;
  }
  __syncthreads();
  return *bc;
}

__device__ __forceinline__ unsigned short f2bf(float f){
  unsigned int u = __float_as_uint(f);
  unsigned int r = (u + 0x7fffu + ((u>>16)&1u)) >> 16;  // RNE
  return (unsigned short)r;
}
__device__ __forceinline__ float bf2f(unsigned int w){ return __uint_as_float(w<<16); }

// ---------------- prep kernels ----------------

__global__ __launch_bounds__(512) void k_em_lse(const float* __restrict__ em, float* __restrict__ em_lse){
  __shared__ float red[8]; __shared__ float bc;
  int r = blockIdx.x;
  const float* row = em + (size_t)r*HM;
  float mx = -INFINITY;
  for(int i=threadIdx.x;i<HM;i+=512) mx = fmaxf(mx, row[i]);
  mx = blockMax512(mx, red, &bc);
  float s = 0.f;
  for(int i=threadIdx.x;i<HM;i+=512) s += expf(row[i]-mx);
  s = blockSum512(s, red, &bc);
  if(threadIdx.x==0) em_lse[r] = mx + logf(s);
}

__global__ __launch_bounds__(512) void k_pri(const float* __restrict__ pri, float* __restrict__ P, float* __restrict__ pric){
  __shared__ float red[8]; __shared__ float bc;
  int j = threadIdx.x;
  float v = pri[j];
  float mx = blockMax512(v, red, &bc);
  float w = expf(v-mx);
  float s = blockSum512(w, red, &bc);
  P[j] = w;
  if(j==0) *pric = -logf(s);
}

// emT[m][j] = bf16( exp(log_em[j][m]) ), LDS-tiled transpose
__global__ __launch_bounds__(256) void k_em_tab(const float* __restrict__ em, const float* __restrict__ em_lse,
                                                unsigned short* __restrict__ emT){
  __shared__ unsigned short tile[64][66];
  __shared__ float lsl[64];
  int m0 = blockIdx.x*64, j0 = blockIdx.y*64;
  int tx = threadIdx.x & 63, ty = threadIdx.x >> 6;
  if(threadIdx.x < 64) lsl[threadIdx.x] = em_lse[j0 + threadIdx.x];
  __syncthreads();
  #pragma unroll
  for(int r=0;r<16;r++){
    int jl = ty*16 + r;
    float v = em[(size_t)(j0+jl)*HM + m0 + tx];
    tile[jl][tx] = f2bf(expf(v - lsl[jl]));
  }
  __syncthreads();
  #pragma unroll
  for(int r=0;r<16;r++){
    int ml = ty*16 + r;
    emT[(size_t)(m0+ml)*HN + j0 + tx] = tile[tx][ml];
  }
}

// column stats of transition col-softmax: cmax[k], csum[k]
__global__ __launch_bounds__(512) void k_trcol(const float* __restrict__ tr,
                                               float* __restrict__ cmax, float* __restrict__ csum){
  __shared__ float red[8]; __shared__ float bc;
  int k = blockIdx.x, j = threadIdx.x;
  float v = tr[(size_t)j*HN + k];
  float mx = blockMax512(v, red, &bc);
  float s  = blockSum512(expf(v-mx), red, &bc);
  if(j==0){ cmax[k] = mx; csum[k] = s; }
}

// row pass: Tr[j,k] -> u4 q=round(Tr*15/rm). Packs nibble pairs (k even: lo=own,
// hi=shfl(k+1)) into TQ4 bytes [j*256 + k/2]. rscale[j]=rm/15; rsT[j]=sum q (bias path).
__global__ __launch_bounds__(512) void k_trrow(const float* __restrict__ tr,
                                               const float* __restrict__ cmax, const float* __restrict__ csum,
                                               unsigned char* __restrict__ TQ4,
                                               float* __restrict__ rscale, int* __restrict__ rsT){
  __shared__ float red[8]; __shared__ float bc;
  int j = blockIdx.x, k = threadIdx.x;
  float v = expf(tr[(size_t)j*HN + k] - cmax[k]) / csum[k];
  float rm = blockMax512(v, red, &bc);
  int q = __float2int_rn(v * (15.0f/rm));          // 0..15
  float qs = blockSum512((float)q, red, &bc);      // exact (<= 7680)
  int qn = __shfl_down(q, 1, 64);                  // partner nibble (k+1)
  if((k & 1)==0){
#if ENC_BIASED
    unsigned char by = (unsigned char)(((q-8)&0xF) | (((qn-8)&0xF)<<4));
#else
    unsigned char by = (unsigned char)((q&0xF) | ((qn&0xF)<<4));
#endif
    TQ4[(size_t)j*256 + (k>>1)] = by;
  }
  if(k==0){ rscale[j] = rm * (1.0f/15.0f); rsT[j] = (int)qs; }
}

// ---------------- forward recurrence ----------------
// 64 blocks (1/batch), 1024 threads = 16 waves. Thread t: state j=t>>1, k-half kh=t&1.
// Tr u4 lives in LDS (128 KB, bank-swizzled chunk index c^((j+4kh)&7) -> b128 reads at
// the 8-words/bank floor). alpha u4 plane (256 B) read wave-uniform (broadcast ~free).
// Finalizer quads (t%4==0) own j-pairs (2f,2f+1): single writer per alpha byte.
// 3 barriers/step (alpha is block-global now). Per-CU/step: LDS ~128KB (~1100-1500 cyc),
// VALU ~32 dot8/thread (~700 cyc/SIMD) -> LDS-BW bound, no register-allocator fight
// (rounds 3-9: any >32-dword register table spills at the allocator's ~56-VGPR target).
__global__ __launch_bounds__(1024)
void k_fwd(const int* __restrict__ x, const int* __restrict__ Tl,
           const unsigned short* __restrict__ emTu,
           const float* __restrict__ P, const float* __restrict__ pric,
           const float* __restrict__ rscaleG, const int* __restrict__ rsTG,
           const unsigned int* __restrict__ TQ4,
           float* __restrict__ out){
  extern __shared__ char smem[];
  unsigned int* trS  = (unsigned int*)smem;            // 131072 B swizzled u4 Tr
  int*          redi = (int*)(smem + 131072);          // [kh][j] partials, 4096 B
  float*        redS = (float*)(smem + 135168);        // 16 wave sums
  float*        redM = (float*)(smem + 135232);        // 16 wave maxes
  float*        redA = (float*)(smem + 135296);        // 16 wave alpha-q sums
  unsigned int* apl  = (unsigned int*)(smem + 135360); // 256 B alpha u4 plane
  int*          xls  = (int*)(smem + 135616);          // 2048 B
  float*        rscL = (float*)(smem + 137664);        // 2048 B
  int*          rsTL = (int*)(smem + 139712);          // 2048 B
  // total 141760 B

  const int t = threadIdx.x, b = blockIdx.x;
  const int j = t>>1, kh = t&1;
  const bool fin = (t&3)==0;
  const int f = t>>2;                                  // finalizer j-pair (2f,2f+1)
  const int LOG15 = 0;  (void)LOG15;

  // stage Tr into LDS with bank swizzle
  for(int d=t; d<32768; d+=1024){
    int jj = d>>6, r = d&63, khh = r>>5, c = (r>>2)&7, e = r&3;
    trS[(jj<<6) + (khh<<5) + (((c ^ ((jj + 4*khh)&7)))<<2) + e] = TQ4[d];
  }
  if(t < HT) xls[t] = x[b*HT + t];
  if(t < HN){ rscL[t] = rscaleG[t]; rsTL[t] = rsTG[t]; }
  int Tb = Tl[b];
  __syncthreads();

  const float LOGC = __logf(15.0f);
  float c_acc = 0.f, lg = 0.f;   // tracked by t==0
  unsigned int emc = 0, emn = 0; // finalizer emission pair (2 bf16 in one dword)

  // ---- t = 0 ----
  {
    int m0 = xls[0];
    float nv0 = 0.f, nv1 = 0.f;
    if(fin){
      unsigned int ep = *(const unsigned int*)(emTu + (size_t)m0*HN + 2*f);
      nv0 = bf2f(ep & 0xffffu) * P[2*f];
      nv1 = bf2f(ep >> 16)     * P[2*f+1];
      float s2 = nv0 + nv1, m2 = fmaxf(nv0, nv1);
      #pragma unroll
      for(int o=4;o<64;o<<=1){ s2 += __shfl_xor(s2,o,64); m2 = fmaxf(m2,__shfl_xor(m2,o,64)); }
      if((t&63)==0){ int w = t>>6; redS[w] = s2; redM[w] = m2; }
      // prefetch symbol-1 emission pair
      int m1 = xls[(Tb>1)?1:0];
      emc = *(const unsigned int*)(emTu + (size_t)m1*HN + 2*f);
    }
    __syncthreads();                                   // B2
    if(fin){
      float4 s0 = ((float4*)redS)[0], s1 = ((float4*)redS)[1], s2_ = ((float4*)redS)[2], s3 = ((float4*)redS)[3];
      float S = ((s0.x+s0.y)+(s0.z+s0.w)) + ((s1.x+s1.y)+(s1.z+s1.w))
              + ((s2_.x+s2_.y)+(s2_.z+s2_.w)) + ((s3.x+s3.y)+(s3.z+s3.w));
      float4 m0_ = ((float4*)redM)[0], m1_ = ((float4*)redM)[1], m2_ = ((float4*)redM)[2], m3_ = ((float4*)redM)[3];
      float M = fmaxf(fmaxf(fmaxf(m0_.x,m0_.y),fmaxf(m0_.z,m0_.w)),
               fmaxf(fmaxf(fmaxf(m1_.x,m1_.y),fmaxf(m1_.z,m1_.w)),
               fmaxf(fmaxf(fmaxf(m2_.x,m2_.y),fmaxf(m2_.z,m2_.w)),
                     fmaxf(fmaxf(m3_.x,m3_.y),fmaxf(m3_.z,m3_.w)))));
      float lS = __logf(S);
      if(t==0){ c_acc = pric[0] + lS; lg = __logf(M) - lS; }
      float inv = 15.0f / M;
      int aq0 = __float2int_rn(nv0 * inv), aq1 = __float2int_rn(nv1 * inv);
#if ENC_BIASED
      ((unsigned char*)apl)[f] = (unsigned char)(((aq0-8)&0xF) | (((aq1-8)&0xF)<<4));
#else
      ((unsigned char*)apl)[f] = (unsigned char)((aq0&0xF) | ((aq1&0xF)<<4));
#endif
      float av = (float)(aq0 + aq1);
      #pragma unroll
      for(int o=4;o<64;o<<=1) av += __shfl_xor(av,o,64);
      if((t&63)==0) redA[t>>6] = av;
    }
  }

  const int cb = (j<<4) + (kh<<3);
  const int sw = (j + 4*kh)&7;

  for(int tt=1; tt<Tb; tt++){
    __syncthreads();                                   // B3: alpha plane + redA ready

    // ---- Phase A: 32 dot8 over this thread's (j, k-half) ----
    int p = 0;
    #pragma unroll
    for(int c=0;c<8;c++){
      uint4 T4 = ((const uint4*)trS)[cb + (c ^ sw)];
      uint4 A4 = ((const uint4*)apl)[(kh<<3) + c];
      p = dot8q(T4.x, A4.x, p);
      p = dot8q(T4.y, A4.y, p);
      p = dot8q(T4.z, A4.z, p);
      p = dot8q(T4.w, A4.w, p);
    }
    redi[(kh<<9) + j] = p;
    __syncthreads();                                   // B1

    float nv0 = 0.f, nv1 = 0.f;
    if(fin){
      // next-step emission prefetch
      int tn = (tt+1 < HT)? tt+1 : HT-1;
      int mn = xls[tn];
      emn = *(const unsigned int*)(emTu + (size_t)mn*HN + 2*f);

      int D0 = redi[2*f]     + redi[512 + 2*f];
      int D1 = redi[2*f + 1] + redi[512 + 2*f + 1];
#if ENC_BIASED
      float4 a0 = ((float4*)redA)[0], a1 = ((float4*)redA)[1], a2 = ((float4*)redA)[2], a3 = ((float4*)redA)[3];
      float asf = ((a0.x+a0.y)+(a0.z+a0.w)) + ((a1.x+a1.y)+(a1.z+a1.w))
                + ((a2.x+a2.y)+(a2.z+a2.w)) + ((a3.x+a3.y)+(a3.z+a3.w));
      int corr = 8*(int)asf - 32768;
      D0 += corr + 8*rsTL[2*f];
      D1 += corr + 8*rsTL[2*f + 1];
#endif
      nv0 = (float)D0 * rscL[2*f]     * bf2f(emc & 0xffffu);
      nv1 = (float)D1 * rscL[2*f + 1] * bf2f(emc >> 16);
      float s2 = nv0 + nv1, m2 = fmaxf(nv0, nv1);
      #pragma unroll
      for(int o=4;o<64;o<<=1){ s2 += __shfl_xor(s2,o,64); m2 = fmaxf(m2,__shfl_xor(m2,o,64)); }
      if((t&63)==0){ int w = t>>6; redS[w] = s2; redM[w] = m2; }
    }
    __syncthreads();                                   // B2
    if(fin){
      float4 s0 = ((float4*)redS)[0], s1 = ((float4*)redS)[1], s2_ = ((float4*)redS)[2], s3 = ((float4*)redS)[3];
      float S = ((s0.x+s0.y)+(s0.z+s0.w)) + ((s1.x+s1.y)+(s1.z+s1.w))
              + ((s2_.x+s2_.y)+(s2_.z+s2_.w)) + ((s3.x+s3.y)+(s3.z+s3.w));
      float4 m0_ = ((float4*)redM)[0], m1_ = ((float4*)redM)[1], m2_ = ((float4*)redM)[2], m3_ = ((float4*)redM)[3];
      float M = fmaxf(fmaxf(fmaxf(m0_.x,m0_.y),fmaxf(m0_.z,m0_.w)),
               fmaxf(fmaxf(fmaxf(m1_.x,m1_.y),fmaxf(m1_.z,m1_.w)),
               fmaxf(fmaxf(fmaxf(m2_.x,m2_.y),fmaxf(m2_.z,m2_.w)),
                     fmaxf(fmaxf(m3_.x,m3_.y),fmaxf(m3_.z,m3_.w)))));
      float lS = __logf(S);
      if(t==0){ c_acc += lS - LOGC + lg; lg = __logf(M) - lS; }
      float inv = 15.0f / M;
      int aq0 = __float2int_rn(nv0 * inv), aq1 = __float2int_rn(nv1 * inv);
#if ENC_BIASED
      ((unsigned char*)apl)[f] = (unsigned char)(((aq0-8)&0xF) | (((aq1-8)&0xF)<<4));
#else
      ((unsigned char*)apl)[f] = (unsigned char)((aq0&0xF) | ((aq1&0xF)<<4));
#endif
      float av = (float)(aq0 + aq1);
      #pragma unroll
      for(int o=4;o<64;o<<=1) av += __shfl_xor(av,o,64);
      if((t&63)==0) redA[t>>6] = av;
      emc = emn;
    }
  }
  if(t==0) out[b] = c_acc;
}

extern "C" void kernel_launch(void* const* d_in, const int* in_sizes, int n_in,
                              void* d_out, int out_size, void* d_ws, size_t ws_size,
                              hipStream_t stream){
  const int*   x   = (const int*)d_in[0];
  const int*   T   = (const int*)d_in[1];
  const float* em  = (const float*)d_in[2];
  const float* tr  = (const float*)d_in[3];
  const float* pri = (const float*)d_in[4];
  float* out = (float*)d_out;

  char* ws = (char*)d_ws;
  float* em_lse = (float*)ws;                                   // 2 KiB
  float* P      = (float*)(ws + 2048);                          // 2 KiB
  float* pric   = (float*)(ws + 4096);                          // 16 B
  float* cmax   = (float*)(ws + 8192);                          // 2 KiB
  float* csum   = (float*)(ws + 10240);                         // 2 KiB
  float* rscale = (float*)(ws + 12288);                         // 2 KiB
  int*   rsT    = (int*)(ws + 14336);                           // 2 KiB
  unsigned short* emT = (unsigned short*)(ws + 24576);          // 4 MiB
  unsigned char*  TQ4 = (unsigned char*)(ws + 24576 + (size_t)HM*HN*2);  // 128 KiB

  k_em_lse<<<HN, 512, 0, stream>>>(em, em_lse);
  k_pri   <<<1,  512, 0, stream>>>(pri, P, pric);
  k_trcol <<<HN, 512, 0, stream>>>(tr, cmax, csum);
  k_trrow <<<HN, 512, 0, stream>>>(tr, cmax, csum, TQ4, rscale, rsT);
  k_em_tab<<<dim3(HM/64, HN/64), 256, 0, stream>>>(em, em_lse, emT);

  const int lds_bytes = 141760;
  (void)hipFuncSetAttribute((const void*)k_fwd, hipFuncAttributeMaxDynamicSharedMemorySize, lds_bytes);
  k_fwd<<<HB, 1024, lds_bytes, stream>>>(x, T, emT, P, pric, rscale, rsT,
                                         (const unsigned int*)TQ4, out);
}

// Round 11
// 676.779 us; speedup vs baseline: 1.7155x; 1.7155x over previous
//
#include <hip/hip_runtime.h>
#include <math.h>

#define HN 512   // hidden states
#define HM 4096  // emission symbols
#define HB 64    // batch
#define HT 512   // max seq len

// ---- 4-bit dot path (encoding must match between prep + fwd) ----
#if __has_builtin(__builtin_amdgcn_udot8)
  #define ENC_BIASED 0
  __device__ __forceinline__ int dot8q(unsigned int a, unsigned int b, int c){
    return (int)__builtin_amdgcn_udot8(a, b, (unsigned int)c, false);
  }
#elif __has_builtin(__builtin_amdgcn_sdot8)
  #define ENC_BIASED 1
  __device__ __forceinline__ int dot8q(unsigned int a, unsigned int b, int c){
    return __builtin_amdgcn_sdot8((int)a, (int)b, c, false);
  }
#else
  #define ENC_BIASED 0
  __device__ __forceinline__ int dot4u8f(unsigned int a, unsigned int b, int c){
#if __has_builtin(__builtin_amdgcn_sdot4)
    return __builtin_amdgcn_sdot4((int)a, (int)b, c, false);   // vals<=15, sign-safe
#else
    c += (int)(a & 0xffu)       * (int)(b & 0xffu);
    c += (int)((a>>8) & 0xffu)  * (int)((b>>8) & 0xffu);
    c += (int)((a>>16) & 0xffu) * (int)((b>>16) & 0xffu);
    c += (int)(a>>24)           * (int)(b>>24);
    return c;
#endif
  }
  __device__ __forceinline__ int dot8q(unsigned int a, unsigned int b, int c){
    unsigned int al = a & 0x0F0F0F0Fu, ah = (a>>4) & 0x0F0F0F0Fu;
    unsigned int bl = b & 0x0F0F0F0Fu, bh = (b>>4) & 0x0F0F0F0Fu;
    c = dot4u8f(al, bl, c);
    return dot4u8f(ah, bh, c);
  }
#endif

__device__ __forceinline__ float rcpf(float x){
#if __has_builtin(__builtin_amdgcn_rcpf)
  return __builtin_amdgcn_rcpf(x);
#else
  return 1.0f / x;
#endif
}

__device__ __forceinline__ float wsum(float v){
  #pragma unroll
  for(int o=32;o>0;o>>=1) v += __shfl_xor(v,o,64);
  return v;
}
__device__ __forceinline__ float wmax(float v){
  #pragma unroll
  for(int o=32;o>0;o>>=1) v = fmaxf(v,__shfl_xor(v,o,64));
  return v;
}

__device__ __forceinline__ float blockSum512(float v, float* red, float* bc){
  v = wsum(v);
  if((threadIdx.x & 63)==0) red[threadIdx.x>>6] = v;
  __syncthreads();
  if(threadIdx.x < 64){
    float s = (threadIdx.x<8)? red[threadIdx.x] : 0.0f;
    #pragma unroll
    for(int o=4;o>0;o>>=1) s += __shfl_xor(s,o,64);
    if(threadIdx.x==0) *bc = s;
  }
  __syncthreads();
  return *bc;
}
__device__ __forceinline__ float blockMax512(float v, float* red, float* bc){
  v = wmax(v);
  if((threadIdx.x & 63)==0) red[threadIdx.x>>6] = v;
  __syncthreads();
  if(threadIdx.x < 64){
    float s = (threadIdx.x<8)? red[threadIdx.x] : -INFINITY;
    #pragma unroll
    for(int o=4;o>0;o>>=1) s = fmaxf(s, __shfl_xor(s,o,64));
    if(threadIdx.x==0) *bc = s;
  }
  __syncthreads();
  return *bc;
}

__device__ __forceinline__ unsigned short f2bf(float f){
  unsigned int u = __float_as_uint(f);
  unsigned int r = (u + 0x7fffu + ((u>>16)&1u)) >> 16;  // RNE
  return (unsigned short)r;
}
__device__ __forceinline__ float bf2f(unsigned int w){ return __uint_as_float(w<<16); }

// ---------------- prep kernels ----------------

__global__ __launch_bounds__(512) void k_em_lse(const float* __restrict__ em, float* __restrict__ em_lse){
  __shared__ float red[8]; __shared__ float bc;
  int r = blockIdx.x;
  const float* row = em + (size_t)r*HM;
  float mx = -INFINITY;
  for(int i=threadIdx.x;i<HM;i+=512) mx = fmaxf(mx, row[i]);
  mx = blockMax512(mx, red, &bc);
  float s = 0.f;
  for(int i=threadIdx.x;i<HM;i+=512) s += expf(row[i]-mx);
  s = blockSum512(s, red, &bc);
  if(threadIdx.x==0) em_lse[r] = mx + logf(s);
}

__global__ __launch_bounds__(512) void k_pri(const float* __restrict__ pri, float* __restrict__ P, float* __restrict__ pric){
  __shared__ float red[8]; __shared__ float bc;
  int j = threadIdx.x;
  float v = pri[j];
  float mx = blockMax512(v, red, &bc);
  float w = expf(v-mx);
  float s = blockSum512(w, red, &bc);
  P[j] = w;
  if(j==0) *pric = -logf(s);
}

// emT[m][j] = bf16( exp(log_em[j][m]) ), LDS-tiled transpose
__global__ __launch_bounds__(256) void k_em_tab(const float* __restrict__ em, const float* __restrict__ em_lse,
                                                unsigned short* __restrict__ emT){
  __shared__ unsigned short tile[64][66];
  __shared__ float lsl[64];
  int m0 = blockIdx.x*64, j0 = blockIdx.y*64;
  int tx = threadIdx.x & 63, ty = threadIdx.x >> 6;
  if(threadIdx.x < 64) lsl[threadIdx.x] = em_lse[j0 + threadIdx.x];
  __syncthreads();
  #pragma unroll
  for(int r=0;r<16;r++){
    int jl = ty*16 + r;
    float v = em[(size_t)(j0+jl)*HM + m0 + tx];
    tile[jl][tx] = f2bf(expf(v - lsl[jl]));
  }
  __syncthreads();
  #pragma unroll
  for(int r=0;r<16;r++){
    int ml = ty*16 + r;
    emT[(size_t)(m0+ml)*HN + j0 + tx] = tile[tx][ml];
  }
}

// column stats of transition col-softmax
__global__ __launch_bounds__(512) void k_trcol(const float* __restrict__ tr,
                                               float* __restrict__ cmax, float* __restrict__ csum){
  __shared__ float red[8]; __shared__ float bc;
  int k = blockIdx.x, j = threadIdx.x;
  float v = tr[(size_t)j*HN + k];
  float mx = blockMax512(v, red, &bc);
  float s  = blockSum512(expf(v-mx), red, &bc);
  if(j==0){ cmax[k] = mx; csum[k] = s; }
}

// row pass: Tr[j,k] -> u4 q = round(Tr*15/rowmax). Nibble layout: byte at
// j*256 + (k>>5)*16 + ((k&31)>>1): lo = even k, hi = k+1 (matches alpha packing).
// rscale[j]=rm/15; rbar[j]= true rowsum - rscale*qsum (residual, bias correction);
// tsumq[j][w] = per-64k-slice qsum (sdot bias path).
__global__ __launch_bounds__(512) void k_trrow(const float* __restrict__ tr,
                                               const float* __restrict__ cmax, const float* __restrict__ csum,
                                               unsigned char* __restrict__ TQ4,
                                               float* __restrict__ rscale, float* __restrict__ rbar,
                                               unsigned short* __restrict__ tsumq){
  __shared__ float red[8]; __shared__ float bc;
  int j = blockIdx.x, k = threadIdx.x;
  float v = expf(tr[(size_t)j*HN + k] - cmax[k]) / csum[k];
  float rm = blockMax512(v, red, &bc);
  int q = __float2int_rn(v * (15.0f/rm));          // 0..15
  float rs = blockSum512(v, red, &bc);             // true row sum
  float qs = blockSum512((float)q, red, &bc);      // total q sum
  float wq = wsum((float)q);                       // per-wave(64k) q sum
  int qn = __shfl_down(q, 1, 64);
  if((k & 1)==0){
#if ENC_BIASED
    unsigned char by = (unsigned char)(((q-8)&0xF) | (((qn-8)&0xF)<<4));
#else
    unsigned char by = (unsigned char)((q&0xF) | ((qn&0xF)<<4));
#endif
    TQ4[(size_t)j*256 + ((k>>5)<<4) + ((k&31)>>1)] = by;
  }
  if((k&63)==0) tsumq[j*8 + (k>>6)] = (unsigned short)(int)wq;
  if(k==0){
    rscale[j] = rm * (1.0f/15.0f);
    rbar[j]   = rs - (rm * (1.0f/15.0f)) * qs;
  }
}

// ---------------- forward recurrence ----------------
// 64 blocks (1/batch), 512 threads = 8 waves. Thread j computes its state's FULL
// 512-k dot in-register (8 per-slice int accumulators, u4 dot8): no k-split, no
// partial buffer, no B1. Tr u4 in LDS (128 KB, chunk-XOR swizzle -> b128 reads at
// the 8-cyc bank floor). alpha plane reads are lane-uniform (broadcast, free).
// Wave w owns alpha slice w: finalize = wave shuffles only. ONE barrier/step;
// read-vs-write hazards removed via ping-pong alpha/stats planes. Normalizer =
// previous step's S (stale divisor is exact: c = log S0_raw + sum log S_t).
// Tr-quant bias correction: D += abar*rbar[j].
__global__ __launch_bounds__(512)
void k_fwd(const int* __restrict__ x, const int* __restrict__ Tl,
           const unsigned short* __restrict__ emTu,
           const float* __restrict__ P, const float* __restrict__ pric,
           const float* __restrict__ rscaleG, const float* __restrict__ rbarG,
           const unsigned short* __restrict__ tsumqG,
           const unsigned int* __restrict__ TQd,
           float* __restrict__ out){
  extern __shared__ char smem[];
  unsigned int*  trS   = (unsigned int*)smem;                  // 131072 B
  uint4*         trS4  = (uint4*)smem;
  uint4*         apl4  = (uint4*)(smem + 131072);              // [2][16] uint4 = 512 B
  unsigned char* aplB  = (unsigned char*)(smem + 131072);
  float*         sigS  = (float*)(smem + 131584);              // [2][8]
  float*         sumS  = (float*)(smem + 131648);              // [2][8]
  float*         aqS   = (float*)(smem + 131712);              // [2][8]
  float*         rawS  = (float*)(smem + 131776);              // [8]
  int*           xls   = (int*)(smem + 131840);                // 2048
  float*         rscL  = (float*)(smem + 133888);              // 2048
  float*         rbarL = (float*)(smem + 135936);              // 2048
  unsigned short* tsumL= (unsigned short*)(smem + 137984);     // 8192
  // total 146176 B

  const int t = threadIdx.x, b = blockIdx.x, w = t>>6, L = t&63;
  const int j = t;

  // ---- stage (swizzled Tr copy + tables) ----
  for(int d=t; d<32768; d+=512){
    int jj = d>>6, dl = d&63, cc = dl>>2, ee = dl&3;
    trS[(jj<<6) + (((cc ^ (jj&15)))<<2) + ee] = TQd[d];
  }
  xls[t]   = x[b*HT + t];
  rscL[t]  = rscaleG[t];
  rbarL[t] = rbarG[t];
  for(int d=t; d<2048; d+=512) ((unsigned int*)tsumL)[d] = ((const unsigned int*)tsumqG)[d];
  int Tb = Tl[b];
  __syncthreads();

  // ---- init (t = 0) ----
  int m = xls[0];
  float e0 = bf2f((unsigned)emTu[(size_t)m*HN + j]);
  float nvr = e0 * P[j];
  {
    float s = wsum(nvr);
    if(L==0) rawS[w] = s;
  }
  __syncthreads();
  float4 q0 = ((float4*)rawS)[0], q1 = ((float4*)rawS)[1];
  float S0 = ((q0.x+q0.y)+(q0.z+q0.w))+((q1.x+q1.y)+(q1.z+q1.w));
  float c_acc = pric[0] + __logf(S0);
  float nvd = nvr * rcpf(S0);
  // quantize + stats into buffer 1 (read by tt=1)
  {
    float Mw = fmaxf(wmax(nvd), 1e-30f);
    float sig = Mw * (1.0f/15.0f);
    int aq = __float2int_rn(nvd * (15.0f * rcpf(Mw)));
    float Sw = wsum(nvd);
#if ENC_BIASED
    float AqSw = wsum((float)aq);
#endif
    int aqn = __shfl_xor(aq, 1, 64);
    if((j&1)==0){
#if ENC_BIASED
      aplB[256 + (j>>1)] = (unsigned char)(((aq-8)&0xF) | (((aqn-8)&0xF)<<4));
#else
      aplB[256 + (j>>1)] = (unsigned char)((aq&0xF) | ((aqn&0xF)<<4));
#endif
    }
    if(L==0){
      sigS[8+w] = sig; sumS[8+w] = Sw;
#if ENC_BIASED
      aqS[8+w] = AqSw;
#endif
    }
  }
  int mn = xls[(Tb>1)?1:0];
  float eC = bf2f((unsigned)emTu[(size_t)mn*HN + j]);
  const float rsc = rscL[j], rbr = rbarL[j];
  const int swz = j & 15;

  for(int tt=1; tt<Tb; tt++){
    __syncthreads();                      // the ONE barrier per step
    const int rb = (tt & 1), wb = rb ^ 1; // read/write buffer indices

    // [a] uniform: previous-step stats
    float4 g0 = ((float4*)(sumS + 8*rb))[0], g1 = ((float4*)(sumS + 8*rb))[1];
    float Sp = ((g0.x+g0.y)+(g0.z+g0.w))+((g1.x+g1.y)+(g1.z+g1.w));
    if(tt > 1) c_acc += __logf(Sp);
    float d_inv = rcpf(Sp);
    float abar  = Sp * (1.0f/512.0f);
    float4 s0 = ((float4*)(sigS + 8*rb))[0], s1 = ((float4*)(sigS + 8*rb))[1];
    float sg[8] = {s0.x,s0.y,s0.z,s0.w,s1.x,s1.y,s1.z,s1.w};
#if ENC_BIASED
    float4 a0 = ((float4*)(aqS + 8*rb))[0], a1 = ((float4*)(aqS + 8*rb))[1];
    float av[8] = {a0.x,a0.y,a0.z,a0.w,a1.x,a1.y,a1.z,a1.w};
    uint4 tq = ((const uint4*)tsumL)[j];
    int ts[8] = {(int)(tq.x&0xffff),(int)(tq.x>>16),(int)(tq.y&0xffff),(int)(tq.y>>16),
                 (int)(tq.z&0xffff),(int)(tq.z>>16),(int)(tq.w&0xffff),(int)(tq.w>>16)};
#endif

    // [b] full-row dot: 16 chunks x 4 dot8, per-slice accumulators
    int acc[8];
    #pragma unroll
    for(int i=0;i<8;i++) acc[i] = 0;
    const uint4* aplR = apl4 + 16*rb;
    #pragma unroll
    for(int c=0;c<16;c++){
      uint4 T = trS4[(j<<4) + (c ^ swz)];
      uint4 A = aplR[c];
      int wi = c>>1;
      acc[wi] = dot8q(T.x, A.x, acc[wi]);
      acc[wi] = dot8q(T.y, A.y, acc[wi]);
      acc[wi] = dot8q(T.z, A.z, acc[wi]);
      acc[wi] = dot8q(T.w, A.w, acc[wi]);
    }

    // [c] combine with per-slice alpha scales (+ sdot bias correction)
    float Af = 0.f;
    #pragma unroll
    for(int i=0;i<8;i++){
#if ENC_BIASED
      int accT = acc[i] + 8*((int)av[i] + ts[i]) - 4096;
      Af += sg[i] * (float)accT;
#else
      Af += sg[i] * (float)acc[i];
#endif
    }
    float D = rsc * Af + abar * rbr;
    nvd = fmaxf(D * eC * d_inv, 0.0f);

    // prefetch next emission
    int tn = (tt+1 < HT)? tt+1 : HT-1;
    mn = xls[tn];
    float eN = bf2f((unsigned)emTu[(size_t)mn*HN + j]);

    // [e] wave-local finalize: quantize vs wave max, write plane wb
    float Mw = fmaxf(wmax(nvd), 1e-30f);
    float sig = Mw * (1.0f/15.0f);
    int aq = __float2int_rn(nvd * (15.0f * rcpf(Mw)));
    float Sw = wsum(nvd);
#if ENC_BIASED
    float AqSw = wsum((float)aq);
#endif
    int aqn = __shfl_xor(aq, 1, 64);
    if((j&1)==0){
#if ENC_BIASED
      aplB[256*wb + (j>>1)] = (unsigned char)(((aq-8)&0xF) | (((aqn-8)&0xF)<<4));
#else
      aplB[256*wb + (j>>1)] = (unsigned char)((aq&0xF) | ((aqn&0xF)<<4));
#endif
    }
    if(L==0){
      sigS[8*wb+w] = sig; sumS[8*wb+w] = Sw;
#if ENC_BIASED
      aqS[8*wb+w] = AqSw;
#endif
    }
    eC = eN;
  }

  // ---- flush last step's S ----
  __syncthreads();
  {
    const int fb = (Tb & 1);
    float4 g0 = ((float4*)(sumS + 8*fb))[0], g1 = ((float4*)(sumS + 8*fb))[1];
    float Sf = ((g0.x+g0.y)+(g0.z+g0.w))+((g1.x+g1.y)+(g1.z+g1.w));
    if(t==0) out[b] = c_acc + __logf(Sf);
  }
}

extern "C" void kernel_launch(void* const* d_in, const int* in_sizes, int n_in,
                              void* d_out, int out_size, void* d_ws, size_t ws_size,
                              hipStream_t stream){
  const int*   x   = (const int*)d_in[0];
  const int*   T   = (const int*)d_in[1];
  const float* em  = (const float*)d_in[2];
  const float* tr  = (const float*)d_in[3];
  const float* pri = (const float*)d_in[4];
  float* out = (float*)d_out;

  char* ws = (char*)d_ws;
  float* em_lse = (float*)ws;                                   // 2 KiB
  float* P      = (float*)(ws + 2048);                          // 2 KiB
  float* pric   = (float*)(ws + 4096);                          // 16 B
  float* cmax   = (float*)(ws + 8192);                          // 2 KiB
  float* csum   = (float*)(ws + 10240);                         // 2 KiB
  float* rscale = (float*)(ws + 12288);                         // 2 KiB
  float* rbar   = (float*)(ws + 14336);                         // 2 KiB
  unsigned short* tsumq = (unsigned short*)(ws + 16384);        // 8 KiB
  unsigned short* emT = (unsigned short*)(ws + 24576);          // 4 MiB
  unsigned char*  TQ4 = (unsigned char*)(ws + 24576 + (size_t)HM*HN*2);  // 128 KiB

  k_em_lse<<<HN, 512, 0, stream>>>(em, em_lse);
  k_pri   <<<1,  512, 0, stream>>>(pri, P, pric);
  k_trcol <<<HN, 512, 0, stream>>>(tr, cmax, csum);
  k_trrow <<<HN, 512, 0, stream>>>(tr, cmax, csum, TQ4, rscale, rbar, tsumq);
  k_em_tab<<<dim3(HM/64, HN/64), 256, 0, stream>>>(em, em_lse, emT);

  const int lds_bytes = 146176;
  (void)hipFuncSetAttribute((const void*)k_fwd, hipFuncAttributeMaxDynamicSharedMemorySize, lds_bytes);
  k_fwd<<<HB, 512, lds_bytes, stream>>>(x, T, emT, P, pric, rscale, rbar, tsumq,
                                        (const unsigned int*)TQ4, out);
}